// Round 1
// baseline (448.342 us; speedup 1.0000x reference)
//
#include <hip/hip_runtime.h>

// ---------------- problem constants ----------------
#define BATCH 2
#define CH    512
#define NTOK  4096      // H*W
#define NH    8
#define HD    64
#define MTOT  (BATCH*NTOK)   // 8192

typedef __attribute__((ext_vector_type(8))) __bf16 bf16x8;
typedef __attribute__((ext_vector_type(4))) float  f32x4;

static __device__ __forceinline__ f32x4 mfma16(bf16x8 a, bf16x8 b, f32x4 c) {
  return __builtin_amdgcn_mfma_f32_16x16x32_bf16(a, b, c, 0, 0, 0);
}

static __device__ __forceinline__ unsigned short f2bf(float f) {
  unsigned int u = __float_as_uint(f);
  u += 0x7fffu + ((u >> 16) & 1u);
  return (unsigned short)(u >> 16);
}

// ---------------- kernel 1: x [B,C,N] -> tokens [B,N,C] (f32 + bf16) ----------------
__global__ __launch_bounds__(256) void k_transpose(const float* __restrict__ x,
                                                   float* __restrict__ tokF,
                                                   unsigned short* __restrict__ tokB) {
  __shared__ float tile[32][33];
  int b  = blockIdx.z;
  int n0 = blockIdx.x * 32;
  int c0 = blockIdx.y * 32;
  int tx = threadIdx.x & 31, ty = threadIdx.x >> 5;  // 32 x 8
#pragma unroll
  for (int i = 0; i < 4; i++) {
    int c = c0 + ty + 8 * i;
    tile[ty + 8 * i][tx] = x[((size_t)b * CH + c) * NTOK + n0 + tx];
  }
  __syncthreads();
#pragma unroll
  for (int i = 0; i < 4; i++) {
    int n = n0 + ty + 8 * i;
    int c = c0 + tx;
    float v = tile[tx][ty + 8 * i];
    size_t idx = ((size_t)b * NTOK + n) * CH + c;
    tokF[idx] = v;
    tokB[idx] = f2bf(v);
  }
}

// ---------------- kernel 2: f32 -> bf16 cast ----------------
__global__ __launch_bounds__(256) void k_cast(const float* __restrict__ in,
                                              unsigned short* __restrict__ out, int n) {
  int i = blockIdx.x * 256 + threadIdx.x;
  if (i < n) out[i] = f2bf(in[i]);
}

// ---------------- GEMM helpers (BM=BN=128, BK=64, 4 waves 2x2) ----------------
#define BK 64

// stage one 128x64 bf16 tile into swizzled LDS; tid in [0,256)
static __device__ __forceinline__ void stage_tile(const unsigned short* __restrict__ src,
                                                  size_t row0, int k0,
                                                  unsigned short* __restrict__ lds, int tid) {
#pragma unroll
  for (int p = 0; p < 4; p++) {
    int row = p * 32 + (tid >> 3);
    int ch  = tid & 7;
    int sw  = ch ^ (row & 7);
    *reinterpret_cast<bf16x8*>(&lds[row * BK + sw * 8]) =
        *reinterpret_cast<const bf16x8*>(&src[(row0 + row) * 512 + k0 + ch * 8]);
  }
}

static __device__ __forceinline__ bf16x8 frag_ld(const unsigned short* __restrict__ lds,
                                                 int row, int ks, int lane) {
  int ch = ((ks << 2) + (lane >> 4)) ^ (row & 7);
  return *reinterpret_cast<const bf16x8*>(&lds[row * BK + ch * 8]);
}

// ---------------- kernel 3: QKV GEMM  tokens[8192,512] x qkv_w^T -> q/k/v [B,H,N,D] bf16 ----------------
__global__ __launch_bounds__(256) void k_gemm_qkv(const unsigned short* __restrict__ A,
                                                  const unsigned short* __restrict__ W,
                                                  const float* __restrict__ bias,
                                                  unsigned short* __restrict__ qb,
                                                  unsigned short* __restrict__ kb,
                                                  unsigned short* __restrict__ vb) {
  __shared__ unsigned short lsA[128 * BK];
  __shared__ unsigned short lsB[128 * BK];
  int bm0 = blockIdx.x * 128;
  int bn0 = blockIdx.y * 128;
  int tid = threadIdx.x, lane = tid & 63, wid = tid >> 6;
  int wm = wid >> 1, wn = wid & 1;

  f32x4 acc[4][4];
  f32x4 zz = {0.f, 0.f, 0.f, 0.f};
#pragma unroll
  for (int i = 0; i < 4; i++)
#pragma unroll
    for (int j = 0; j < 4; j++) acc[i][j] = zz;

  for (int k0 = 0; k0 < 512; k0 += BK) {
    stage_tile(A, (size_t)bm0, k0, lsA, tid);
    stage_tile(W, (size_t)bn0, k0, lsB, tid);
    __syncthreads();
#pragma unroll
    for (int ks = 0; ks < 2; ks++) {
      bf16x8 af[4], bfr[4];
#pragma unroll
      for (int t = 0; t < 4; t++) {
        af[t]  = frag_ld(lsA, wm * 64 + t * 16 + (lane & 15), ks, lane);
        bfr[t] = frag_ld(lsB, wn * 64 + t * 16 + (lane & 15), ks, lane);
      }
#pragma unroll
      for (int mt = 0; mt < 4; mt++)
#pragma unroll
        for (int nt = 0; nt < 4; nt++) acc[mt][nt] = mfma16(af[mt], bfr[nt], acc[mt][nt]);
    }
    __syncthreads();
  }
  // epilogue: scatter to head-major q/k/v
#pragma unroll
  for (int nt = 0; nt < 4; nt++) {
    int j = bn0 + wn * 64 + nt * 16 + (lane & 15);
    float bj = bias[j];
    int which = j >> 9;
    int cp = j & 511;
    int h = cp >> 6, d = cp & 63;
    unsigned short* dst = (which == 0) ? qb : (which == 1) ? kb : vb;
#pragma unroll
    for (int mt = 0; mt < 4; mt++) {
#pragma unroll
      for (int r = 0; r < 4; r++) {
        int m = bm0 + wm * 64 + mt * 16 + 4 * (lane >> 4) + r;
        int b = m >> 12, n = m & 4095;
        dst[(((size_t)(b * NH + h) * NTOK + n) << 6) + d] = f2bf(acc[mt][nt][r] + bj);
      }
    }
  }
}

// ---------------- kernel 4: flash attention ----------------
// grid: (64 q-tiles, 16 bh). block 256 = 4 waves, 16 q-rows each.
__global__ __launch_bounds__(256) void k_attn(const unsigned short* __restrict__ Q,
                                              const unsigned short* __restrict__ K,
                                              const unsigned short* __restrict__ V,
                                              unsigned short* __restrict__ O) {
  __shared__ unsigned short lsp[4][16 * 32];
  int bh = blockIdx.y;
  int tid = threadIdx.x, lane = tid & 63, wid = tid >> 6;
  int qw = blockIdx.x * 64 + wid * 16;
  const unsigned short* Qp = Q + (size_t)bh * NTOK * HD;
  const unsigned short* Kp = K + (size_t)bh * NTOK * HD;
  const unsigned short* Vp = V + (size_t)bh * NTOK * HD;
  unsigned short* P = &lsp[wid][0];

  bf16x8 qf[2];
  int qrow = qw + (lane & 15);
#pragma unroll
  for (int ks = 0; ks < 2; ks++)
    qf[ks] = *reinterpret_cast<const bf16x8*>(&Qp[(size_t)qrow * HD + ks * 32 + 8 * (lane >> 4)]);

  f32x4 oacc[4];
  f32x4 zz = {0.f, 0.f, 0.f, 0.f};
#pragma unroll
  for (int dt = 0; dt < 4; dt++) oacc[dt] = zz;
  float m_r[4], l_r[4];
#pragma unroll
  for (int r = 0; r < 4; r++) { m_r[r] = -1e30f; l_r[r] = 0.f; }

  for (int kv0 = 0; kv0 < NTOK; kv0 += 32) {
    f32x4 s[2] = {zz, zz};
#pragma unroll
    for (int ct = 0; ct < 2; ct++) {
      int krow = kv0 + ct * 16 + (lane & 15);
#pragma unroll
      for (int ks = 0; ks < 2; ks++) {
        bf16x8 kf = *reinterpret_cast<const bf16x8*>(&Kp[(size_t)krow * HD + ks * 32 + 8 * (lane >> 4)]);
        s[ct] = mfma16(qf[ks], kf, s[ct]);
      }
    }
    float t[4], alpha[4], rsum[4], pv[2][4];
#pragma unroll
    for (int r = 0; r < 4; r++) {
      s[0][r] *= 0.125f; s[1][r] *= 0.125f;
      t[r] = fmaxf(s[0][r], s[1][r]);
    }
#pragma unroll
    for (int off = 1; off < 16; off <<= 1)
#pragma unroll
      for (int r = 0; r < 4; r++) t[r] = fmaxf(t[r], __shfl_xor(t[r], off));
#pragma unroll
    for (int r = 0; r < 4; r++) {
      float mnew = fmaxf(m_r[r], t[r]);
      alpha[r] = __expf(m_r[r] - mnew);
      m_r[r] = mnew;
      pv[0][r] = __expf(s[0][r] - mnew);
      pv[1][r] = __expf(s[1][r] - mnew);
      rsum[r] = pv[0][r] + pv[1][r];
    }
#pragma unroll
    for (int off = 1; off < 16; off <<= 1)
#pragma unroll
      for (int r = 0; r < 4; r++) rsum[r] += __shfl_xor(rsum[r], off);
#pragma unroll
    for (int r = 0; r < 4; r++) l_r[r] = l_r[r] * alpha[r] + rsum[r];
#pragma unroll
    for (int dt = 0; dt < 4; dt++)
#pragma unroll
      for (int r = 0; r < 4; r++) oacc[dt][r] *= alpha[r];
    // P -> LDS (bf16, swizzled), then read back as A-fragment
#pragma unroll
    for (int ct = 0; ct < 2; ct++)
#pragma unroll
      for (int r = 0; r < 4; r++) {
        int row = 4 * (lane >> 4) + r;
        int col = (lane & 15) + 16 * ct;
        P[row * 32 + (col ^ ((row & 3) << 3))] = f2bf(pv[ct][r]);
      }
    bf16x8 pf = *reinterpret_cast<const bf16x8*>(
        &P[(lane & 15) * 32 + ((8 * (lane >> 4)) ^ ((lane & 3) << 3))]);
    // PV
#pragma unroll
    for (int dt = 0; dt < 4; dt++) {
      union { unsigned short u[8]; bf16x8 v; } vu;
      const unsigned short* vbase = Vp + (size_t)(kv0 + 8 * (lane >> 4)) * HD + dt * 16 + (lane & 15);
#pragma unroll
      for (int i = 0; i < 8; i++) vu.u[i] = vbase[(size_t)i * HD];
      oacc[dt] = mfma16(pf, vu.v, oacc[dt]);
    }
  }
  // finalize
  int b = bh >> 3, h = bh & 7;
  float inv[4];
#pragma unroll
  for (int r = 0; r < 4; r++) inv[r] = 1.0f / l_r[r];
#pragma unroll
  for (int dt = 0; dt < 4; dt++)
#pragma unroll
    for (int r = 0; r < 4; r++) {
      int n = qw + 4 * (lane >> 4) + r;
      int d = dt * 16 + (lane & 15);
      O[((size_t)(b * NTOK + n)) * CH + h * HD + d] = f2bf(oacc[dt][r] * inv[r]);
    }
}

// ---------------- kernel 5: out-proj GEMM + bias + residual -> res (f32) ----------------
__global__ __launch_bounds__(256) void k_gemm_out(const unsigned short* __restrict__ A,
                                                  const unsigned short* __restrict__ W,
                                                  const float* __restrict__ bias,
                                                  const float* __restrict__ tokF,
                                                  float* __restrict__ res) {
  __shared__ unsigned short lsA[128 * BK];
  __shared__ unsigned short lsB[128 * BK];
  int bm0 = blockIdx.x * 128;
  int bn0 = blockIdx.y * 128;
  int tid = threadIdx.x, lane = tid & 63, wid = tid >> 6;
  int wm = wid >> 1, wn = wid & 1;

  f32x4 acc[4][4];
  f32x4 zz = {0.f, 0.f, 0.f, 0.f};
#pragma unroll
  for (int i = 0; i < 4; i++)
#pragma unroll
    for (int j = 0; j < 4; j++) acc[i][j] = zz;

  for (int k0 = 0; k0 < 512; k0 += BK) {
    stage_tile(A, (size_t)bm0, k0, lsA, tid);
    stage_tile(W, (size_t)bn0, k0, lsB, tid);
    __syncthreads();
#pragma unroll
    for (int ks = 0; ks < 2; ks++) {
      bf16x8 af[4], bfr[4];
#pragma unroll
      for (int t = 0; t < 4; t++) {
        af[t]  = frag_ld(lsA, wm * 64 + t * 16 + (lane & 15), ks, lane);
        bfr[t] = frag_ld(lsB, wn * 64 + t * 16 + (lane & 15), ks, lane);
      }
#pragma unroll
      for (int mt = 0; mt < 4; mt++)
#pragma unroll
        for (int nt = 0; nt < 4; nt++) acc[mt][nt] = mfma16(af[mt], bfr[nt], acc[mt][nt]);
    }
    __syncthreads();
  }
#pragma unroll
  for (int nt = 0; nt < 4; nt++) {
    int j = bn0 + wn * 64 + nt * 16 + (lane & 15);
    float bj = bias[j];
#pragma unroll
    for (int mt = 0; mt < 4; mt++) {
#pragma unroll
      for (int r = 0; r < 4; r++) {
        int m = bm0 + wm * 64 + mt * 16 + 4 * (lane >> 4) + r;
        size_t idx = (size_t)m * CH + j;
        res[idx] = acc[mt][nt][r] + bj + tokF[idx];
      }
    }
  }
}

// ---------------- kernel 6: LayerNorm over C + transposed write ----------------
__global__ __launch_bounds__(256) void k_ln(const float* __restrict__ res,
                                            const float* __restrict__ g,
                                            const float* __restrict__ bb,
                                            float* __restrict__ y) {
  __shared__ float smean[64], srstd[64];
  int m0 = blockIdx.x * 64;
  int tid = threadIdx.x, lane = tid & 63, wid = tid >> 6;
  for (int t = 0; t < 16; t++) {
    int idx = wid * 16 + t;
    const float* row = res + (size_t)(m0 + idx) * CH;
    float s = 0.f, ss = 0.f;
#pragma unroll
    for (int i = 0; i < 8; i++) {
      float v = row[lane + 64 * i];
      s += v; ss += v * v;
    }
#pragma unroll
    for (int off = 1; off < 64; off <<= 1) {
      s += __shfl_xor(s, off);
      ss += __shfl_xor(ss, off);
    }
    if (lane == 0) {
      float mean = s * (1.0f / CH);
      float var = ss * (1.0f / CH) - mean * mean;
      smean[idx] = mean;
      srstd[idx] = rsqrtf(var + 1e-5f);
    }
  }
  __syncthreads();
  int b = m0 >> 12, n0 = m0 & 4095;
  int tn = tid & 63;
  int cq = tid >> 6;
  float mn = smean[tn], rs = srstd[tn];
  const float* rrow = res + (size_t)(m0 + tn) * CH;
  for (int c = cq; c < CH; c += 4) {
    float v = (rrow[c] - mn) * rs * g[c] + bb[c];
    y[((size_t)b * CH + c) * NTOK + n0 + tn] = v;
  }
}

// ---------------- launch ----------------
extern "C" void kernel_launch(void* const* d_in, const int* in_sizes, int n_in,
                              void* d_out, int out_size, void* d_ws, size_t ws_size,
                              hipStream_t stream) {
  const float* x    = (const float*)d_in[0];
  const float* qkvw = (const float*)d_in[1];
  const float* qkvb = (const float*)d_in[2];
  const float* outw = (const float*)d_in[3];
  const float* outb = (const float*)d_in[4];
  const float* lng  = (const float*)d_in[5];
  const float* lnb  = (const float*)d_in[6];
  float* y = (float*)d_out;

  char* ws = (char*)d_ws;
  size_t off = 0;
  auto nxt = [&](size_t bytes) -> void* {
    void* p = ws + off;
    off += (bytes + 255) & ~(size_t)255;
    return p;
  };
  unsigned short* tokB = (unsigned short*)nxt((size_t)MTOT * CH * 2);
  float*          tokF = (float*)nxt((size_t)MTOT * CH * 4);
  unsigned short* wqkv = (unsigned short*)nxt((size_t)3 * CH * CH * 2);
  unsigned short* wout = (unsigned short*)nxt((size_t)CH * CH * 2);
  unsigned short* qb   = (unsigned short*)nxt((size_t)MTOT * CH * 2);
  unsigned short* kb   = (unsigned short*)nxt((size_t)MTOT * CH * 2);
  unsigned short* vb   = (unsigned short*)nxt((size_t)MTOT * CH * 2);
  unsigned short* ao   = (unsigned short*)nxt((size_t)MTOT * CH * 2);
  float*          resb = (float*)nxt((size_t)MTOT * CH * 4);
  if (off > ws_size) return;  // fail loudly via wrong output rather than corrupt memory

  k_transpose<<<dim3(NTOK / 32, CH / 32, BATCH), 256, 0, stream>>>(x, tokF, tokB);
  k_cast<<<(3 * CH * CH + 255) / 256, 256, 0, stream>>>(qkvw, wqkv, 3 * CH * CH);
  k_cast<<<(CH * CH + 255) / 256, 256, 0, stream>>>(outw, wout, CH * CH);
  k_gemm_qkv<<<dim3(MTOT / 128, (3 * CH) / 128), 256, 0, stream>>>(tokB, wqkv, qkvb, qb, kb, vb);
  k_attn<<<dim3(NTOK / 64, BATCH * NH), 256, 0, stream>>>(qb, kb, vb, ao);
  k_gemm_out<<<dim3(MTOT / 128, CH / 128), 256, 0, stream>>>(ao, wout, outb, tokF, resb);
  k_ln<<<MTOT / 64, 256, 0, stream>>>(resb, lng, lnb, y);
}